// Round 4
// baseline (203.092 us; speedup 1.0000x reference)
//
#include <hip/hip_runtime.h>

#define NV 512
#define BV 8
#define KSEL 26163
#define NNv (NV*NV)          // 262144
#define BKv (BV*KSEL)        // 209304
#define CAPB 32768
#define DELTA 1e-4f          // score error bound (paranoid; worst-case ~3e-5)

typedef unsigned int u32;
typedef __attribute__((ext_vector_type(8))) _Float16 f16x8;
typedef __attribute__((ext_vector_type(4))) float f32x4;

// ---------------- embed: x -> emb -> ai, aj, ajb(=aj+b1) --------------------
__global__ void __launch_bounds__(256) k_embed(
    const float* __restrict__ x, const float* __restrict__ w_emb,
    const float* __restrict__ b_emb, const float* __restrict__ w_proj,
    const float* __restrict__ b_proj, const float* __restrict__ w1,
    const float* __restrict__ b1,
    float* __restrict__ ai, float* __restrict__ aj, float* __restrict__ ajb) {
    __shared__ float sh[4][64];
    __shared__ float se[4][64];
    const int c = threadIdx.x;        // 0..63
    const int lr = threadIdx.y;       // 0..3
    const int row = blockIdx.x * 4 + lr;
    const float xv = x[row];
    sh[lr][c] = fmaxf(fmaf(xv, w_emb[c], b_emb[c]), 0.f);
    __syncthreads();
    float e = 0.f;
#pragma unroll
    for (int h = 0; h < 64; ++h) e = fmaf(sh[lr][h], w_proj[h * 64 + c], e);
    se[lr][c] = e + b_proj[c];
    __syncthreads();
    float a0 = 0.f, a1 = 0.f;
#pragma unroll
    for (int h = 0; h < 64; ++h) {
        const float ev = se[lr][h];
        a0 = fmaf(ev, w1[h * 64 + c], a0);
        a1 = fmaf(ev, w1[(64 + h) * 64 + c], a1);
    }
    ai[row * 64 + c] = a0;
    aj[row * 64 + c] = a1;
    ajb[row * 64 + c] = a1 + b1[c];
}

// ---------------- approx pair scorer: double-f16 (Ootomo) MFMA --------------
// h2 = w2^T t with t = relu(ai+ajb). Split: th=(f16)(t*256), tl=(f16)((t*256-th)*2048)
// wh=(f16)w2, wl=(f16)((w2-wh)*2048). acc_m = wh*th (scale 2^8);
// acc_c = wh*tl + wl*th (scale 2^19). h2 = acc_m*2^-8 + acc_c*2^-19.
// mfma_f32_16x16x32_f16 layouts: A row=lane&15, k=(lane>>4)*8+e;
// B col=lane&15, k=(lane>>4)*8+e; D col=lane&15, row=(lane>>4)*4+reg (m89).
__global__ void __launch_bounds__(256) k_pairs_mfma(
    const float* __restrict__ ai, const float* __restrict__ ajb,
    const float* __restrict__ w2, const float* __restrict__ b2,
    const float* __restrict__ w3, const float* __restrict__ b3,
    float* __restrict__ probs) {
    __shared__ float s_ai[2048];     // 32 i x 64 h
    const int tid = threadIdx.x;
    const int b = blockIdx.z;
    const int i0 = blockIdx.y << 5;  // 32 i per block
    const int j0 = blockIdx.x << 6;  // 64 j per block
    {
        const int r = tid >> 3, c8 = (tid & 7) << 3;
        const float* src = &ai[(((b << 9) + i0 + r) << 6) + c8];
        *(float4*)&s_ai[(r << 6) + c8]     = *(const float4*)&src[0];
        *(float4*)&s_ai[(r << 6) + c8 + 4] = *(const float4*)&src[4];
    }
    const int lane = tid & 63;
    const int wv = tid >> 6;         // wave -> j-slice of 16
    const int lp = lane & 15;
    const int lg = lane >> 4;        // k-group
    const int j = j0 + (wv << 4) + lp;

    float ajr[2][8];                 // h = ch*32 + lg*8 + e
    {
        const float* base = &ajb[(((b << 9) + j) << 6) + (lg << 3)];
        *(float4*)&ajr[0][0] = *(const float4*)&base[0];
        *(float4*)&ajr[0][4] = *(const float4*)&base[4];
        *(float4*)&ajr[1][0] = *(const float4*)&base[32];
        *(float4*)&ajr[1][4] = *(const float4*)&base[36];
    }
    f16x8 Ah[2][2], Al[2][2];        // w2^T hi/lo fragments [ktile][hchunk]
#pragma unroll
    for (int kt = 0; kt < 2; ++kt)
#pragma unroll
        for (int ch = 0; ch < 2; ++ch)
#pragma unroll
            for (int e = 0; e < 8; ++e) {
                const float wv2 = w2[((ch << 5) + (lg << 3) + e) * 32 + (kt << 4) + lp];
                const _Float16 wh = (_Float16)wv2;
                Ah[kt][ch][e] = wh;
                Al[kt][ch][e] = (_Float16)((wv2 - (float)wh) * 2048.0f);
            }
    float b2r[2][4], w3r[2][4];
#pragma unroll
    for (int kt = 0; kt < 2; ++kt)
#pragma unroll
        for (int r = 0; r < 4; ++r) {
            b2r[kt][r] = b2[(kt << 4) + (lg << 2) + r];
            w3r[kt][r] = w3[(kt << 4) + (lg << 2) + r];
        }
    const float b3v = b3[0];
    __syncthreads();

    for (int i = 0; i < 32; ++i) {
        float ar[2][8];
        const float* arow = &s_ai[(i << 6) + (lg << 3)];
        *(float4*)&ar[0][0] = *(const float4*)&arow[0];
        *(float4*)&ar[0][4] = *(const float4*)&arow[4];
        *(float4*)&ar[1][0] = *(const float4*)&arow[32];
        *(float4*)&ar[1][4] = *(const float4*)&arow[36];
        f16x8 Bh0, Bh1, Bl0, Bl1;
#pragma unroll
        for (int e = 0; e < 8; ++e) {
            const float t0 = fmaxf(ar[0][e] + ajr[0][e], 0.f) * 256.0f;
            const float t1 = fmaxf(ar[1][e] + ajr[1][e], 0.f) * 256.0f;
            const _Float16 h0 = (_Float16)t0;
            const _Float16 h1 = (_Float16)t1;
            Bh0[e] = h0; Bl0[e] = (_Float16)((t0 - (float)h0) * 2048.0f);
            Bh1[e] = h1; Bl1[e] = (_Float16)((t1 - (float)h1) * 2048.0f);
        }
        f32x4 am0 = {0.f,0.f,0.f,0.f}, am1 = {0.f,0.f,0.f,0.f};
        f32x4 ac0 = {0.f,0.f,0.f,0.f}, ac1 = {0.f,0.f,0.f,0.f};
        am0 = __builtin_amdgcn_mfma_f32_16x16x32_f16(Ah[0][0], Bh0, am0, 0, 0, 0);
        am0 = __builtin_amdgcn_mfma_f32_16x16x32_f16(Ah[0][1], Bh1, am0, 0, 0, 0);
        ac0 = __builtin_amdgcn_mfma_f32_16x16x32_f16(Ah[0][0], Bl0, ac0, 0, 0, 0);
        ac0 = __builtin_amdgcn_mfma_f32_16x16x32_f16(Ah[0][1], Bl1, ac0, 0, 0, 0);
        ac0 = __builtin_amdgcn_mfma_f32_16x16x32_f16(Al[0][0], Bh0, ac0, 0, 0, 0);
        ac0 = __builtin_amdgcn_mfma_f32_16x16x32_f16(Al[0][1], Bh1, ac0, 0, 0, 0);
        am1 = __builtin_amdgcn_mfma_f32_16x16x32_f16(Ah[1][0], Bh0, am1, 0, 0, 0);
        am1 = __builtin_amdgcn_mfma_f32_16x16x32_f16(Ah[1][1], Bh1, am1, 0, 0, 0);
        ac1 = __builtin_amdgcn_mfma_f32_16x16x32_f16(Ah[1][0], Bl0, ac1, 0, 0, 0);
        ac1 = __builtin_amdgcn_mfma_f32_16x16x32_f16(Ah[1][1], Bl1, ac1, 0, 0, 0);
        ac1 = __builtin_amdgcn_mfma_f32_16x16x32_f16(Al[1][0], Bh0, ac1, 0, 0, 0);
        ac1 = __builtin_amdgcn_mfma_f32_16x16x32_f16(Al[1][1], Bh1, ac1, 0, 0, 0);
        float s = 0.f;
#pragma unroll
        for (int r = 0; r < 4; ++r) {
            const float h2 = fmaf(ac0[r], 1.9073486328125e-6f, am0[r] * 0.00390625f);
            s = fmaf(fmaxf(h2 + b2r[0][r], 0.f), w3r[0][r], s);
        }
#pragma unroll
        for (int r = 0; r < 4; ++r) {
            const float h2 = fmaf(ac1[r], 1.9073486328125e-6f, am1[r] * 0.00390625f);
            s = fmaf(fmaxf(h2 + b2r[1][r], 0.f), w3r[1][r], s);
        }
        s += __shfl_xor(s, 16);
        s += __shfl_xor(s, 32);
        const float p = 1.f / (1.f + expf(-(s + b3v)));
        if (lane < 16) probs[(((b << 9) + i0 + i) << 9) + j] = p;
    }
}

// ---------------- symmetrize in place, zero diagonal ------------------------
__global__ void k_sym(float* __restrict__ P) {
    const int b = blockIdx.y;
    int rem = blockIdx.x, ta = 0;
    while (rem >= 16 - ta) { rem -= 16 - ta; ++ta; }
    const int tb = ta + rem;
    const int r  = threadIdx.x >> 3;
    const int c4 = (threadIdx.x & 7) << 2;
    const int i = (ta << 5) + r;
    const int j = (tb << 5) + c4;
    float* Pb = P + b * NNv;
    float4 a = *(const float4*)&Pb[(i << 9) + j];
    float t0 = Pb[((j + 0) << 9) + i];
    float t1 = Pb[((j + 1) << 9) + i];
    float t2 = Pb[((j + 2) << 9) + i];
    float t3 = Pb[((j + 3) << 9) + i];
    __syncthreads();
    float4 o;
    o.x = (i == j + 0) ? 0.f : 0.5f * (a.x + t0);
    o.y = (i == j + 1) ? 0.f : 0.5f * (a.y + t1);
    o.z = (i == j + 2) ? 0.f : 0.5f * (a.z + t2);
    o.w = (i == j + 3) ? 0.f : 0.5f * (a.w + t3);
    *(float4*)&Pb[(i << 9) + j] = o;
    Pb[((j + 0) << 9) + i] = o.x;
    Pb[((j + 1) << 9) + i] = o.y;
    Pb[((j + 2) << 9) + i] = o.z;
    Pb[((j + 3) << 9) + i] = o.w;
}

// ---------------- 3x 8-bit radix passes -> 24-bit bin of K-th ---------------
template <int PASS>
__global__ void k_hist(const float* __restrict__ probs,
                       const u32* __restrict__ prefix, u32* __restrict__ hist) {
    __shared__ u32 lh[1024];
    const int t = threadIdx.x;
    lh[t] = 0u; lh[256 + t] = 0u; lh[512 + t] = 0u; lh[768 + t] = 0u;
    __syncthreads();
    const int b = blockIdx.y;
    u32 pref = 0u;
    if constexpr (PASS > 0) pref = prefix[b];
    const float* Pb = probs + b * NNv;
    const int base = blockIdx.x * 4096 + t;
    const int rep = (t & 3) << 8;
#pragma unroll
    for (int e = 0; e < 16; ++e) {
        const u32 key = __float_as_uint(Pb[base + e * 256]);
        bool ok = true;
        if constexpr (PASS > 0) ok = ((key >> (32 - 8 * PASS)) == pref);
        if (ok) atomicAdd(&lh[rep + ((key >> (24 - 8 * PASS)) & 255u)], 1u);
    }
    __syncthreads();
    const u32 sum = lh[t] + lh[256 + t] + lh[512 + t] + lh[768 + t];
    if (sum) atomicAdd(&hist[b * 256 + t], sum);
}

template <int FIRST>
__global__ void k_selp(const u32* __restrict__ hist, u32* __restrict__ prefix,
                       u32* __restrict__ rem) {
    __shared__ u32 s[256];
    const int b = blockIdx.x, t = threadIdx.x;
    s[t] = hist[b * 256 + t];
    __syncthreads();
    for (int off = 1; off < 256; off <<= 1) {
        const u32 v = (t + off < 256) ? s[t + off] : 0u;
        __syncthreads();
        s[t] += v;
        __syncthreads();
    }
    const u32 remv = FIRST ? (u32)KSEL : rem[b];
    const u32 above = (t < 255) ? s[t + 1] : 0u;
    if (s[t] >= remv && above < remv) {
        rem[b] = remv - above;
        prefix[b] = (prefix[b] << 8) | (u32)t;
    }
}

__global__ void k_thr(const u32* __restrict__ prefix, float* __restrict__ thr) {
    const int b = threadIdx.x;
    if (b >= 8) return;
    const u32 p24 = prefix[b];
    thr[b]     = __uint_as_float(p24 << 8) - 2.f * DELTA;          // Tlo
    thr[8 + b] = __uint_as_float((p24 + 1u) << 8) + 2.f * DELTA;   // Thi
}

// ---------------- collect band + count definite-ins -------------------------
__global__ void __launch_bounds__(256) k_band(
    const float* __restrict__ P, const float* __restrict__ thr,
    u32* __restrict__ C_in, u32* __restrict__ bandCnt, u32* __restrict__ bandIdx) {
    __shared__ u32 lidx[1024];
    __shared__ u32 lcnt, lhi, gbase;
    const int b = blockIdx.y, blk = blockIdx.x, t = threadIdx.x;
    if (t == 0) { lcnt = 0u; lhi = 0u; }
    __syncthreads();
    const float Tlo = thr[b], Thi = thr[8 + b];
    const int fi0 = blk * 1024 + t * 4;
    const float4 v = *(const float4*)&P[b * NNv + fi0];
    const float vv[4] = {v.x, v.y, v.z, v.w};
    u32 hc = 0;
#pragma unroll
    for (int q = 0; q < 4; ++q) {
        const float xq = vv[q];
        if (xq > Thi) ++hc;
        else if (xq >= Tlo) { u32 p = atomicAdd(&lcnt, 1u); lidx[p] = (u32)(fi0 + q); }
    }
    if (hc) atomicAdd(&lhi, hc);
    __syncthreads();
    if (t == 0) {
        if (lhi) atomicAdd(&C_in[b], lhi);
        gbase = lcnt ? atomicAdd(&bandCnt[b], lcnt) : 0u;
    }
    __syncthreads();
    for (u32 p = t; p < lcnt; p += 256) {
        const u32 g = gbase + p;
        if (g < (u32)CAPB) bandIdx[b * CAPB + g] = lidx[p];
    }
}

// ---------------- exact recompute of band pairs (bit-identical to R1) -------
__device__ __forceinline__ float exact_p(const float* __restrict__ rai,
                                         const float* __restrict__ raj,
                                         const float* __restrict__ s_w2,
                                         const float* __restrict__ s_b1,
                                         const float* __restrict__ s_b2,
                                         const float* __restrict__ s_w3,
                                         float b3v) {
    float acc[32];
#pragma unroll
    for (int k = 0; k < 32; ++k) acc[k] = 0.f;
#pragma unroll 1
    for (int h0 = 0; h0 < 64; h0 += 16) {
        float A[16], J[16];
#pragma unroll
        for (int q = 0; q < 4; ++q) {
            *(float4*)&A[q * 4] = *(const float4*)&rai[h0 + q * 4];
            *(float4*)&J[q * 4] = *(const float4*)&raj[h0 + q * 4];
        }
#pragma unroll
        for (int hh = 0; hh < 16; ++hh) {
            const float tv = fmaxf((A[hh] + J[hh]) + s_b1[h0 + hh], 0.f);
#pragma unroll
            for (int k = 0; k < 32; ++k) acc[k] = fmaf(tv, s_w2[(h0 + hh) * 32 + k], acc[k]);
        }
    }
    float d = 0.f;
#pragma unroll
    for (int k = 0; k < 32; ++k) d = fmaf(fmaxf(acc[k] + s_b2[k], 0.f), s_w3[k], d);
    return 1.f / (1.f + expf(-(d + b3v)));
}

__global__ void __launch_bounds__(256) k_band_exact(
    const float* __restrict__ ai, const float* __restrict__ aj,
    const float* __restrict__ b1, const float* __restrict__ w2,
    const float* __restrict__ b2, const float* __restrict__ w3,
    const float* __restrict__ b3, const u32* __restrict__ bandCnt,
    const u32* __restrict__ bandIdx, float* __restrict__ bandVal) {
    __shared__ float s_w2[2048];
    __shared__ float s_b1[64], s_b2[32], s_w3[32];
    const int b = blockIdx.y, t = threadIdx.x;
    {
        const int o = t * 8;
        *(float4*)&s_w2[o]     = *(const float4*)&w2[o];
        *(float4*)&s_w2[o + 4] = *(const float4*)&w2[o + 4];
        if (t < 64) s_b1[t] = b1[t];
        if (t < 32) { s_b2[t] = b2[t]; s_w3[t] = w3[t]; }
    }
    __syncthreads();
    const u32 nb = min(bandCnt[b], (u32)CAPB);
    const float b3v = b3[0];
    for (u32 e = blockIdx.x * 256 + t; e < nb; e += 2048) {
        const u32 idx = bandIdx[b * CAPB + e];
        const int i = (int)(idx >> 9), j = (int)(idx & 511u);
        const float* ri  = &ai[(((b << 9) + i)) << 6];
        const float* rj  = &aj[(((b << 9) + j)) << 6];
        const float* rj2 = &ai[(((b << 9) + j)) << 6];
        const float* ri2 = &aj[(((b << 9) + i)) << 6];
        const float p1 = exact_p(ri, rj, s_w2, s_b1, s_b2, s_w3, b3v);   // P[i][j]
        const float p2 = exact_p(rj2, ri2, s_w2, s_b1, s_b2, s_w3, b3v); // P[j][i]
        bandVal[b * CAPB + e] = 0.5f * (p1 + p2);
    }
}

// ---------------- select within band: binary search + index ties ------------
__global__ void __launch_bounds__(256) k_band_select(
    const u32* __restrict__ bandCnt, const u32* __restrict__ C_in,
    const u32* __restrict__ bandIdx, const float* __restrict__ bandVal,
    u32* __restrict__ bitmap) {
    __shared__ u32 red[256];
    __shared__ u32 tie[8192];
    __shared__ u32 tieCnt;
    const int b = blockIdx.x, t = threadIdx.x;
    const u32 nb = min(bandCnt[b], (u32)CAPB);
    const u32 Kp = (u32)KSEL - C_in[b];
    const u32* vb = (const u32*)(bandVal + b * CAPB);
    const u32* ib = bandIdx + b * CAPB;
    u32* bm = bitmap + b * 8192;
    u32 mn = 0xFFFFFFFFu, mx = 0u;
    for (u32 e = t; e < nb; e += 256) { const u32 v = vb[e]; mn = min(mn, v); mx = max(mx, v); }
    red[t] = mn; __syncthreads();
    for (int s = 128; s > 0; s >>= 1) { if (t < s) red[t] = min(red[t], red[t + s]); __syncthreads(); }
    const u32 glo = red[0]; __syncthreads();
    red[t] = mx; __syncthreads();
    for (int s = 128; s > 0; s >>= 1) { if (t < s) red[t] = max(red[t], red[t + s]); __syncthreads(); }
    const u32 ghi = red[0]; __syncthreads();
    u32 lo = glo, hi = ghi;
    while (lo < hi) {
        const u32 mid = lo + ((hi - lo) >> 1);
        u32 c = 0;
        for (u32 e = t; e < nb; e += 256) c += (vb[e] > mid);
        red[t] = c; __syncthreads();
        for (int s = 128; s > 0; s >>= 1) { if (t < s) red[t] += red[t + s]; __syncthreads(); }
        const u32 tot = red[0]; __syncthreads();
        if (tot >= Kp) lo = mid + 1; else hi = mid;
    }
    const u32 Tx = lo;
    if (t == 0) tieCnt = 0u;
    __syncthreads();
    u32 c = 0;
    for (u32 e = t; e < nb; e += 256) {
        const u32 v = vb[e];
        if (v > Tx) {
            ++c;
            const u32 idx = ib[e];
            atomicOr(&bm[idx >> 5], 1u << (idx & 31u));
        } else if (v == Tx) {
            const u32 p = atomicAdd(&tieCnt, 1u);
            if (p < 8192u) tie[p] = ib[e];
        }
    }
    red[t] = c; __syncthreads();
    for (int s = 128; s > 0; s >>= 1) { if (t < s) red[t] += red[t + s]; __syncthreads(); }
    const u32 Ap = red[0]; __syncthreads();
    const u32 Rp = Kp - Ap;
    const u32 E = min(tieCnt, 8192u);
    for (u32 e = t; e < E; e += 256) {
        const u32 my = tie[e];
        u32 r = 0;
        for (u32 m = 0; m < E; ++m) r += (tie[m] < my);
        if (r < Rp) atomicOr(&bm[my >> 5], 1u << (my & 31u));
    }
}

// ---------------- compaction: count / scan / write --------------------------
__global__ void k_count(const float* __restrict__ P, const float* __restrict__ thr,
                        const u32* __restrict__ bitmap, u32* __restrict__ bgt) {
    __shared__ u32 sg[256];
    const int b = blockIdx.y, blk = blockIdx.x, t = threadIdx.x;
    const float Thi = thr[8 + b];
    const int fi0 = blk * 1024 + t * 4;
    const float4 v = *(const float4*)&P[b * NNv + fi0];
    const float vv[4] = {v.x, v.y, v.z, v.w};
    const u32 w = bitmap[b * 8192 + (fi0 >> 5)];
    const u32 sh = (u32)(fi0 & 31);
    u32 cnt = 0;
#pragma unroll
    for (int q = 0; q < 4; ++q) cnt += (vv[q] > Thi) || ((w >> (sh + q)) & 1u);
    sg[t] = cnt;
    __syncthreads();
    for (int s = 128; s > 0; s >>= 1) { if (t < s) sg[t] += sg[t + s]; __syncthreads(); }
    if (t == 0) bgt[b * 256 + blk] = sg[0];
}

__global__ void k_scan1(const u32* __restrict__ bgt, u32* __restrict__ goff) {
    __shared__ u32 sg[256];
    const int b = blockIdx.x, t = threadIdx.x;
    const u32 g = bgt[b * 256 + t];
    sg[t] = g;
    __syncthreads();
    for (int off = 1; off < 256; off <<= 1) {
        const u32 a = (t >= off) ? sg[t - off] : 0u;
        __syncthreads();
        sg[t] += a;
        __syncthreads();
    }
    goff[b * 256 + t] = sg[t] - g;
}

__global__ void k_write(const float* __restrict__ P, const float* __restrict__ thr,
                        const u32* __restrict__ bitmap, const u32* __restrict__ goff,
                        float* __restrict__ out) {
    __shared__ u32 sg[256];
    const int b = blockIdx.y, blk = blockIdx.x, t = threadIdx.x;
    const float Thi = thr[8 + b];
    const int pbase = b * NNv;
    const int fi0 = blk * 1024 + t * 4;
    const float4 v = *(const float4*)&P[pbase + fi0];
    const float vv[4] = {v.x, v.y, v.z, v.w};
    const u32 w = bitmap[b * 8192 + (fi0 >> 5)];
    const u32 sh = (u32)(fi0 & 31);
    bool sel[4];
    u32 cnt = 0;
#pragma unroll
    for (int q = 0; q < 4; ++q) {
        sel[q] = (vv[q] > Thi) || ((w >> (sh + q)) & 1u);
        cnt += sel[q];
    }
    sg[t] = cnt;
    __syncthreads();
    for (int off = 1; off < 256; off <<= 1) {
        const u32 a = (t >= off) ? sg[t - off] : 0u;
        __syncthreads();
        sg[t] += a;
        __syncthreads();
    }
    u32 pos = goff[b * 256 + blk] + sg[t] - cnt;
#pragma unroll
    for (int q = 0; q < 4; ++q) {
        if (sel[q]) {
            if (pos < (u32)KSEL) {
                const int g = b * KSEL + (int)pos;
                const int fi = fi0 + q;
                const int row = fi >> 9, col = fi & 511;
                out[g]           = (float)(row + (b << 9));
                out[BKv + g]     = (float)(col + (b << 9));
                out[2 * BKv + g] = vv[q];
                out[3 * BKv + pbase + fi] = vv[q];
            }
            ++pos;
        }
    }
}

// ---------------------------------------------------------------------------
extern "C" void kernel_launch(void* const* d_in, const int* in_sizes, int n_in,
                              void* d_out, int out_size, void* d_ws, size_t ws_size,
                              hipStream_t stream) {
    const float* x      = (const float*)d_in[0];
    const float* w_emb  = (const float*)d_in[1];
    const float* b_emb  = (const float*)d_in[2];
    const float* w_proj = (const float*)d_in[3];
    const float* b_proj = (const float*)d_in[4];
    const float* w1     = (const float*)d_in[5];
    const float* b1     = (const float*)d_in[6];
    const float* w2     = (const float*)d_in[7];
    const float* b2     = (const float*)d_in[8];
    const float* w3     = (const float*)d_in[9];
    const float* b3     = (const float*)d_in[10];
    (void)in_sizes; (void)n_in; (void)ws_size;

    char* ws = (char*)d_ws;
    float* ai      = (float*)(ws);                    // 1 MiB
    float* aj      = (float*)(ws + 1048576);          // 1 MiB
    float* ajb     = (float*)(ws + 2097152);          // 1 MiB
    float* probs   = (float*)(ws + 3145728);          // 8 MiB
    u32*   bandIdx = (u32*)  (ws + 11534336);         // 1 MiB
    float* bandVal = (float*)(ws + 12582912);         // 1 MiB
    const size_t SOFF = 13631488;
    u32*   hist0   = (u32*)  (ws + SOFF);             // 8 KiB
    u32*   hist1   = (u32*)  (ws + SOFF + 8192);      // 8 KiB
    u32*   hist2   = (u32*)  (ws + SOFF + 16384);     // 8 KiB
    u32*   prefix  = (u32*)  (ws + SOFF + 24576);     // 32 B
    u32*   rem     = (u32*)  (ws + SOFF + 24608);     // 32 B
    float* thr     = (float*)(ws + SOFF + 24640);     // 64 B: Tlo[8], Thi[8]
    u32*   C_in    = (u32*)  (ws + SOFF + 24704);     // 32 B
    u32*   bandCnt = (u32*)  (ws + SOFF + 24736);     // 32 B
    u32*   bitmap  = (u32*)  (ws + SOFF + 24832);     // 256 KiB
    u32*   bgt     = (u32*)  (ws + SOFF + 286976);    // 8 KiB
    u32*   goff    = (u32*)  (ws + SOFF + 295168);    // 8 KiB

    float* out = (float*)d_out;

    hipMemsetAsync(d_out, 0, (size_t)out_size * sizeof(float), stream);
    hipMemsetAsync(ws + SOFF, 0, 286976, stream);     // hists..bitmap inclusive

    k_embed<<<1024, dim3(64, 4, 1), 0, stream>>>(x, w_emb, b_emb, w_proj, b_proj, w1, b1, ai, aj, ajb);
    k_pairs_mfma<<<dim3(8, 16, 8), 256, 0, stream>>>(ai, ajb, w2, b2, w3, b3, probs);
    k_sym<<<dim3(136, 8), 256, 0, stream>>>(probs);
    k_hist<0><<<dim3(64, 8), 256, 0, stream>>>(probs, prefix, hist0);
    k_selp<1><<<8, 256, 0, stream>>>(hist0, prefix, rem);
    k_hist<1><<<dim3(64, 8), 256, 0, stream>>>(probs, prefix, hist1);
    k_selp<0><<<8, 256, 0, stream>>>(hist1, prefix, rem);
    k_hist<2><<<dim3(64, 8), 256, 0, stream>>>(probs, prefix, hist2);
    k_selp<0><<<8, 256, 0, stream>>>(hist2, prefix, rem);
    k_thr<<<1, 64, 0, stream>>>(prefix, thr);
    k_band<<<dim3(256, 8), 256, 0, stream>>>(probs, thr, C_in, bandCnt, bandIdx);
    k_band_exact<<<dim3(8, 8), 256, 0, stream>>>(ai, aj, b1, w2, b2, w3, b3, bandCnt, bandIdx, bandVal);
    k_band_select<<<8, 256, 0, stream>>>(bandCnt, C_in, bandIdx, bandVal, bitmap);
    k_count<<<dim3(256, 8), 256, 0, stream>>>(probs, thr, bitmap, bgt);
    k_scan1<<<8, 256, 0, stream>>>(bgt, goff);
    k_write<<<dim3(256, 8), 256, 0, stream>>>(probs, thr, bitmap, goff, out);
}